// Round 7
// baseline (219.951 us; speedup 1.0000x reference)
//
#include <hip/hip_runtime.h>

#define NB 8
#define NC 256
#define NL 2048
#define SCALE 0.0625f   // C^-0.5 = 1/16

typedef __attribute__((ext_vector_type(8))) __bf16 bf16x8;
typedef __attribute__((ext_vector_type(4))) float f32x4;
typedef __attribute__((ext_vector_type(16))) float f32x16;
typedef __attribute__((ext_vector_type(4))) unsigned int u32x4;
typedef __attribute__((ext_vector_type(2))) unsigned int u32x2;
typedef __attribute__((ext_vector_type(4))) unsigned short u16x4;
typedef __attribute__((ext_vector_type(8))) unsigned short u16x8;

// round-to-nearest-even fp32 -> bf16 bits
static __device__ __forceinline__ unsigned short f2b(float f) {
    unsigned int u = __builtin_bit_cast(unsigned int, f);
    u += 0x7fffu + ((u >> 16) & 1u);
    return (unsigned short)(u >> 16);
}

// ---------------------------------------------------------------------------
// Prep A: Wq/Wk/Wv fp32 -> bf16, concatenated [3][256][256].
// ---------------------------------------------------------------------------
__global__ void wconv_kernel(const float* __restrict__ Wq,
                             const float* __restrict__ Wk,
                             const float* __restrict__ Wv,
                             unsigned short* __restrict__ Wbf)
{
    const int base = (blockIdx.x * 256 + threadIdx.x) * 4;
    const int mat  = base >> 16;
    const int off  = base & 65535;
    const float* W = (mat == 0) ? Wq : (mat == 1) ? Wk : Wv;
    float4 w = *(const float4*)&W[off];
    u16x4 p = {f2b(w.x), f2b(w.y), f2b(w.z), f2b(w.w)};
    *(u16x4*)&Wbf[base] = p;
}

// ---------------------------------------------------------------------------
// Prep B: x [B][C][L] fp32 -> xT [B][L][C] bf16 (transpose via LDS).
// ---------------------------------------------------------------------------
__global__ __launch_bounds__(256, 2) void xprep_kernel(
    const float* __restrict__ x, unsigned short* __restrict__ xT)
{
    const int b  = blockIdx.z;
    const int c0 = blockIdx.y * 64;
    const int l0 = blockIdx.x * 64;
    const int t  = threadIdx.x;

    __shared__ unsigned short Tr[64][68];

    #pragma unroll
    for (int p = 0; p < 4; ++p) {
        const int c  = p * 16 + (t >> 4);
        const int lg = t & 15;
        float4 xv = *(const float4*)&x[((size_t)(b * NC + c0 + c)) * NL + l0 + lg * 4];
        u16x4 pk = {f2b(xv.x), f2b(xv.y), f2b(xv.z), f2b(xv.w)};
        *(u16x4*)&Tr[c][lg * 4] = pk;
    }
    __syncthreads();
    #pragma unroll
    for (int j = 0; j < 2; ++j) {
        const int chunk = t + 256 * j;      // 0..511
        const int l  = chunk >> 3;
        const int ck = chunk & 7;
        u16x8 o;
        #pragma unroll
        for (int i = 0; i < 8; ++i) o[i] = Tr[ck * 8 + i][l];
        *(u16x8*)&xT[((size_t)(b * NL + l0 + l)) * NC + c0 + ck * 8] = o;
    }
}

// ---------------------------------------------------------------------------
// Kernel 1: QKV projection via MFMA (verbatim from verified state).
// ---------------------------------------------------------------------------
__global__ __launch_bounds__(256, 2) void qkv_mfma(
    const unsigned short* __restrict__ xT,
    const unsigned short* __restrict__ Wbf,
    const float* __restrict__ bq, const float* __restrict__ bk,
    const float* __restrict__ bv,
    unsigned short* __restrict__ qT, unsigned short* __restrict__ kT,
    unsigned short* __restrict__ vo)
{
    const int raw = blockIdx.x;
    const int b   = raw & 7;          // XCD-pinned batch
    const int rem = raw >> 3;         // 0..95
    const int mat = rem >> 5;         // 0..2
    const int lt0 = (rem & 31) * 64;
    const int t    = threadIdx.x;
    const int w    = t >> 6;
    const int lane = t & 63;
    const int ln15 = lane & 15;
    const int quad = lane >> 4;

    __shared__ __align__(16) unsigned short XT[64 * 256];  // [l][c] swz, 32 KB
    __shared__ __align__(16) unsigned short WC[256 * 64];  // [o][c-chunk] swz, 32 KB

    const unsigned short* Wm = Wbf + mat * 65536;
    const float* bias = (mat == 0) ? bq : (mat == 1) ? bk : bv;

    float bvals[4][4];
    #pragma unroll
    for (int ot = 0; ot < 4; ++ot)
        #pragma unroll
        for (int r = 0; r < 4; ++r)
            bvals[ot][r] = bias[w * 64 + ot * 16 + quad * 4 + r];

    #pragma unroll
    for (int s = 0; s < 8; ++s) {
        const int il = w * 8 + s;
        const int n  = il * 2 + (lane >> 5);
        const int p  = lane & 31;
        const int g  = p ^ (n & 15);
        const unsigned short* gp = &xT[((size_t)(b * NL + lt0 + n)) * NC + g * 8];
        __builtin_amdgcn_global_load_lds(
            (const __attribute__((address_space(1))) unsigned int*)gp,
            (__attribute__((address_space(3))) unsigned int*)&XT[il * 512],
            16, 0, 0);
    }

    f32x4 acc[4][4];
    #pragma unroll
    for (int i = 0; i < 4; ++i)
        #pragma unroll
        for (int j = 0; j < 4; ++j) acc[i][j] = f32x4{0.f, 0.f, 0.f, 0.f};

    for (int k0 = 0; k0 < 4; ++k0) {
        if (k0) __syncthreads();
        #pragma unroll
        for (int s = 0; s < 8; ++s) {
            const int il = w * 8 + s;
            const int o  = il * 8 + (lane >> 3);
            const int p  = lane & 7;
            const int g  = p ^ (o & 7);
            const unsigned short* gp = &Wm[(size_t)o * NC + k0 * 64 + g * 8];
            __builtin_amdgcn_global_load_lds(
                (const __attribute__((address_space(1))) unsigned int*)gp,
                (__attribute__((address_space(3))) unsigned int*)&WC[il * 512],
                16, 0, 0);
        }
        __syncthreads();

        #pragma unroll
        for (int ks = 0; ks < 2; ++ks) {
            bf16x8 xf[4];
            #pragma unroll
            for (int lt = 0; lt < 4; ++lt) {
                const int l  = lt * 16 + ln15;
                const int kc = k0 * 8 + ks * 4 + quad;
                const int pp = kc ^ (l & 15);
                xf[lt] = __builtin_bit_cast(bf16x8, *(const u32x4*)&XT[l * 256 + pp * 8]);
            }
            #pragma unroll
            for (int ot = 0; ot < 4; ++ot) {
                const int o  = w * 64 + ot * 16 + ln15;
                const int pp = (ks * 4 + quad) ^ (o & 7);
                bf16x8 wf = __builtin_bit_cast(bf16x8, *(const u32x4*)&WC[o * 64 + pp * 8]);
                #pragma unroll
                for (int lt = 0; lt < 4; ++lt)
                    acc[ot][lt] = __builtin_amdgcn_mfma_f32_16x16x32_bf16(
                                      wf, xf[lt], acc[ot][lt], 0, 0, 0);
            }
        }
    }

    if (mat < 2) {
        unsigned short* out = (mat == 0) ? qT : kT;
        #pragma unroll
        for (int ot = 0; ot < 4; ++ot) {
            const int o_base = w * 64 + ot * 16 + quad * 4;
            #pragma unroll
            for (int lt = 0; lt < 4; ++lt) {
                const int l = lt0 + lt * 16 + ln15;
                u16x4 pk;
                #pragma unroll
                for (int r = 0; r < 4; ++r)
                    pk[r] = f2b(acc[ot][lt][r] + bvals[ot][r]);
                *(u16x4*)&out[((size_t)(b * NL + l)) * NC + o_base] = pk;
            }
        }
    } else {
        #pragma unroll
        for (int ot = 0; ot < 4; ++ot)
            #pragma unroll
            for (int lt = 0; lt < 4; ++lt) {
                const int l = lt0 + lt * 16 + ln15;
                #pragma unroll
                for (int r = 0; r < 4; ++r) {
                    const int o = w * 64 + ot * 16 + quad * 4 + r;
                    vo[((size_t)(b * NC + o)) * NL + l] = f2b(acc[ot][lt][r] + bvals[ot][r]);
                }
            }
    }
}

// ---------------------------------------------------------------------------
// Kernel 2: MFMA flash attention + residual, 32x32x16 MFMA edition.
// grid 256, block 1024 = 16 waves, 4 waves/SIMD. Roles:
//   waves 0..3  = QK: (qh=w>>1, kh=w&1). One 32x32 S^T block each, 16 MFMAs
//                 over 256 ch, A=K(LDS), B=Q resident (64 VGPR). exp, pack,
//                 4x ds_write_b64 into swizzled P, denom via shfl_xor(32).
//   waves 4..11 = PV: idx=w-4 (qh=idx>>2, cb=idx&3). ctx[32q][64c], K=64:
//                 4 k-steps x (1 P b128 read reused for 2 c-blocks + 2 V
//                 b128 reads + 2 MFMAs). ctx = 2x f32x16.
//   waves 12..15= STAGE: all global_load_lds issues (8 K + 8 V segments ea).
// Pipeline (verified R5 schedule): region r stages K(r+1),V(r); computes
// QK(r) and PV(r-1); P double-buffered; ONE barrier per region.
// 32x32x16 = 16 FLOP/operand-byte -> LDS traffic 360 -> 232 KB/region.
// Fragment layouts: A row=lane&31, k=(lane>>5)*8+i; B col=lane&31, same k;
// C/D col=lane&31, row=(reg&3)+8*(reg>>2)+4*(lane>>5)  [m74/m101 verified].
// ---------------------------------------------------------------------------
__global__ __launch_bounds__(1024, 4) void attn_kernel(
    const unsigned short* __restrict__ qT,
    const unsigned short* __restrict__ kT,
    const unsigned short* __restrict__ v,
    const float* __restrict__ x,
    float* __restrict__ out)
{
    const int raw  = blockIdx.x;
    const int b    = raw & 7;         // XCD-pinned batch
    const int l0   = (raw >> 3) * 64;
    const int t    = threadIdx.x;
    const int w    = t >> 6;          // 0..15
    const int lane = t & 63;
    const int c31  = lane & 31;
    const int h    = lane >> 5;       // 0/1

    __shared__ __align__(16) char smem[147968];
    unsigned short* Kb0 = (unsigned short*)smem;             // 32 KB
    unsigned short* Kb1 = (unsigned short*)(smem + 32768);   // 32 KB
    unsigned short* Vb0 = (unsigned short*)(smem + 65536);   // 32 KB
    unsigned short* Vb1 = (unsigned short*)(smem + 98304);   // 32 KB
    char* P0 = smem + 131072;                                //  8 KB [64q][64k] swz16
    char* P1 = smem + 139264;                                //  8 KB
    float* denomP = (float*)(smem + 147456);                 // 512 B [2 kh][64 q]
    float (*buf)[68] = (float(*)[68])smem;                   // epilogue alias 69.6 KB

    const bool isQK = (w < 4);
    const bool isPV = (w >= 4) && (w < 12);
    const int qkqh = w >> 1;          // QK: q half
    const int kh   = w & 1;           // QK: key half
    const int pvqh = (w - 4) >> 2;    // PV: q half
    const int cbase = ((w - 4) & 3) * 64;  // PV: channel base

    // ---- QK waves: Q resident as B-operand: col q = qh*32+c31, k = h*8+i ----
    bf16x8 qf[16];
    if (isQK) {
        const size_t qrow = ((size_t)b * NL + l0 + qkqh * 32 + c31) * NC;
        #pragma unroll
        for (int s = 0; s < 16; ++s)
            qf[s] = __builtin_bit_cast(bf16x8,
                        *(const u32x4*)&qT[qrow + s * 16 + h * 8]);
    }

    f32x16 ctxA = {};
    f32x16 ctxB = {};
    float dacc = 0.f;

    auto stageK = [&](int mt, unsigned short* Kd) {
        const int m0 = mt * 64;
        #pragma unroll
        for (int s = 0; s < 8; ++s) {
            const int il = (w - 12) * 8 + s;           // 0..31
            const int n  = il * 2 + h;
            const int g  = c31 ^ (n & 15);
            const unsigned short* gp = &kT[((size_t)b * NL + m0 + n) * NC + g * 8];
            __builtin_amdgcn_global_load_lds(
                (const __attribute__((address_space(1))) unsigned int*)gp,
                (__attribute__((address_space(3))) unsigned int*)&Kd[il * 512],
                16, 0, 0);
        }
    };
    auto stageV = [&](int mt, unsigned short* Vd) {
        const int m0 = mt * 64;
        #pragma unroll
        for (int s = 0; s < 8; ++s) {
            const int il = (w - 12) * 8 + s;           // 0..31
            const int c  = il * 8 + (lane >> 3);
            const int g  = (lane & 7) ^ (c & 7);
            const unsigned short* gp = &v[((size_t)(b * NC + c)) * NL + m0 + g * 8];
            __builtin_amdgcn_global_load_lds(
                (const __attribute__((address_space(1))) unsigned int*)gp,
                (__attribute__((address_space(3))) unsigned int*)&Vd[il * 512],
                16, 0, 0);
        }
    };

    if (w >= 12) stageK(0, Kb0);
    __syncthreads();   // K(0) ready

    const int qq = qkqh * 32 + c31;   // QK: this lane's q (S^T col)
    const int pq = pvqh * 32 + c31;   // PV: this lane's q row (A-frag)

    for (int r = 0; r <= 32; ++r) {
        if (w >= 12) {
            // ---- STAGE waves: K one region ahead, V current ----
            if (r < 31) stageK(r + 1, ((r + 1) & 1) ? Kb1 : Kb0);
            if (r < 32) stageV(r, (r & 1) ? Vb1 : Vb0);
        } else if (isQK) {
            if (r < 32) {
                const unsigned short* Kd = (r & 1) ? Kb1 : Kb0;
                char* Pw = (r & 1) ? P1 : P0;
                const int n = kh * 32 + c31;       // key row
                f32x16 sacc = {};
                #pragma unroll
                for (int s = 0; s < 16; ++s) {
                    const int g = (s * 2 + h) ^ (n & 15);
                    bf16x8 kf = __builtin_bit_cast(bf16x8,
                                  *(const u32x4*)&Kd[n * 256 + g * 8]);
                    sacc = __builtin_amdgcn_mfma_f32_32x32x16_bf16(
                               kf, qf[s], sacc, 0, 0, 0);
                }
                // exp + pack 4-key runs + swizzled b64 writes + denom partial
                float rs = 0.f;
                #pragma unroll
                for (int kr = 0; kr < 4; ++kr) {
                    float e0 = __expf(sacc[kr * 4 + 0] * SCALE);
                    float e1 = __expf(sacc[kr * 4 + 1] * SCALE);
                    float e2 = __expf(sacc[kr * 4 + 2] * SCALE);
                    float e3 = __expf(sacc[kr * 4 + 3] * SCALE);
                    rs += (e0 + e1) + (e2 + e3);
                    unsigned int d0 = (unsigned int)f2b(e0) | ((unsigned int)f2b(e1) << 16);
                    unsigned int d1 = (unsigned int)f2b(e2) | ((unsigned int)f2b(e3) << 16);
                    const int s16 = (kh * 4 + kr) ^ (qq & 7);
                    *(u32x2*)(Pw + qq * 128 + s16 * 16 + 8 * h) = u32x2{d0, d1};
                }
                rs += __shfl_xor(rs, 32, 64);
                dacc += rs;
            }
        } else {
            if (r > 0) {
                const char* Pr = ((r - 1) & 1) ? P1 : P0;
                const unsigned short* Vd = ((r - 1) & 1) ? Vb1 : Vb0;
                #pragma unroll
                for (int ks = 0; ks < 4; ++ks) {
                    const int sp = (ks * 2 + h) ^ (pq & 7);
                    bf16x8 pa = __builtin_bit_cast(bf16x8,
                                  *(const u32x4*)(Pr + pq * 128 + sp * 16));
                    const int cA = cbase + c31;
                    const int gA = (ks * 2 + h) ^ (cA & 7);
                    bf16x8 vbA = __builtin_bit_cast(bf16x8,
                                   *(const u32x4*)&Vd[cA * 64 + gA * 8]);
                    ctxA = __builtin_amdgcn_mfma_f32_32x32x16_bf16(
                               pa, vbA, ctxA, 0, 0, 0);
                    const int cB = cbase + 32 + c31;
                    const int gB = (ks * 2 + h) ^ (cB & 7);
                    bf16x8 vbB = __builtin_bit_cast(bf16x8,
                                   *(const u32x4*)&Vd[cB * 64 + gB * 8]);
                    ctxB = __builtin_amdgcn_mfma_f32_32x32x16_bf16(
                               pa, vbB, ctxB, 0, 0, 0);
                }
            }
        }

        __syncthreads();   // region end: P visible, staging landed, bufs safe
    }

    // ---- denominators: QK waves publish (both halves hold full sum) ----
    if (isQK && lane < 32)
        denomP[kh * 64 + qkqh * 32 + c31] = dacc;
    __syncthreads();

    // ---- PV waves: normalize + write to epilogue buf [256c][68q-pad] ----
    if (isPV) {
        #pragma unroll
        for (int reg = 0; reg < 16; ++reg) {
            const int ql = (reg & 3) + 8 * (reg >> 2) + 4 * h;
            const int qg = pvqh * 32 + ql;
            const float rinv = 1.0f / (denomP[qg] + denomP[64 + qg]);
            buf[cbase + c31][qg]      = ctxA[reg] * rinv;
            buf[cbase + 32 + c31][qg] = ctxB[reg] * rinv;
        }
    }
    __syncthreads();

    #pragma unroll
    for (int p = 0; p < 4; ++p) {
        const int f  = t + 1024 * p;      // 0..4095
        const int c  = f >> 4;
        const int lg = (f & 15) * 4;
        const size_t idx = ((size_t)(b * NC + c)) * NL + l0 + lg;
        float4 xv = *(const float4*)&x[idx];
        float4 cv = *(const float4*)&buf[c][lg];
        float4 o = make_float4(cv.x + xv.x, cv.y + xv.y, cv.z + xv.z, cv.w + xv.w);
        *(float4*)&out[idx] = o;
    }
}

// ---------------------------------------------------------------------------
extern "C" void kernel_launch(void* const* d_in, const int* in_sizes, int n_in,
                              void* d_out, int out_size, void* d_ws, size_t ws_size,
                              hipStream_t stream) {
    const float* x  = (const float*)d_in[0];
    const float* Wq = (const float*)d_in[1];
    const float* bq = (const float*)d_in[2];
    const float* Wk = (const float*)d_in[3];
    const float* bk = (const float*)d_in[4];
    const float* Wv = (const float*)d_in[5];
    const float* bv = (const float*)d_in[6];
    float* out = (float*)d_out;

    const size_t plane = (size_t)NB * NC * NL;       // 4.19M elems
    unsigned short* qT  = (unsigned short*)d_ws;
    unsigned short* kT  = qT + plane;
    unsigned short* v   = kT + plane;
    unsigned short* xT  = v + plane;
    unsigned short* Wbf = xT + plane;                // 3*65536 elems

    wconv_kernel<<<192, 256, 0, stream>>>(Wq, Wk, Wv, Wbf);

    dim3 gx(NL / 64, NC / 64, NB);                   // (32, 4, 8)
    xprep_kernel<<<gx, 256, 0, stream>>>(x, xT);

    qkv_mfma<<<768, 256, 0, stream>>>(xT, Wbf, bq, bk, bv, qT, kT, v);

    attn_kernel<<<256, 1024, 0, stream>>>(qT, kT, v, x, out);
}

// Round 8
// 149.976 us; speedup vs baseline: 1.4666x; 1.4666x over previous
//
#include <hip/hip_runtime.h>

#define NB 8
#define NC 256
#define NL 2048
#define SCALE 0.0625f   // C^-0.5 = 1/16

typedef __attribute__((ext_vector_type(8))) __bf16 bf16x8;
typedef __attribute__((ext_vector_type(4))) float f32x4;
typedef __attribute__((ext_vector_type(4))) unsigned int u32x4;
typedef __attribute__((ext_vector_type(2))) unsigned int u32x2;
typedef __attribute__((ext_vector_type(4))) unsigned short u16x4;
typedef __attribute__((ext_vector_type(8))) unsigned short u16x8;

// round-to-nearest-even fp32 -> bf16 bits
static __device__ __forceinline__ unsigned short f2b(float f) {
    unsigned int u = __builtin_bit_cast(unsigned int, f);
    u += 0x7fffu + ((u >> 16) & 1u);
    return (unsigned short)(u >> 16);
}

// ---------------------------------------------------------------------------
// Prep (merged): blocks 0..1023 = x [B][C][L] fp32 -> xT [B][L][C] bf16
// (transpose via LDS, indexing identical to the old xprep grid (32,4,8));
// blocks 1024..1215 = Wq/Wk/Wv fp32 -> bf16 concat [3][256][256].
// ---------------------------------------------------------------------------
__global__ __launch_bounds__(256) void prep_kernel(
    const float* __restrict__ x, unsigned short* __restrict__ xT,
    const float* __restrict__ Wq, const float* __restrict__ Wk,
    const float* __restrict__ Wv, unsigned short* __restrict__ Wbf)
{
    const int blk = blockIdx.x;
    const int t   = threadIdx.x;

    __shared__ unsigned short Tr[64][68];

    if (blk >= 1024) {
        // ---- weight convert (old wconv_kernel) ----
        const int base = ((blk - 1024) * 256 + t) * 4;
        const int mat  = base >> 16;
        const int off  = base & 65535;
        const float* W = (mat == 0) ? Wq : (mat == 1) ? Wk : Wv;
        float4 w = *(const float4*)&W[off];
        u16x4 p = {f2b(w.x), f2b(w.y), f2b(w.z), f2b(w.w)};
        *(u16x4*)&Wbf[base] = p;
        return;
    }

    // ---- x transpose (old xprep_kernel); blk = l-tile + 32*(c-tile + 4*b) ----
    const int b  = blk >> 7;
    const int c0 = ((blk >> 5) & 3) * 64;
    const int l0 = (blk & 31) * 64;

    #pragma unroll
    for (int p = 0; p < 4; ++p) {
        const int c  = p * 16 + (t >> 4);
        const int lg = t & 15;
        float4 xv = *(const float4*)&x[((size_t)(b * NC + c0 + c)) * NL + l0 + lg * 4];
        u16x4 pk = {f2b(xv.x), f2b(xv.y), f2b(xv.z), f2b(xv.w)};
        *(u16x4*)&Tr[c][lg * 4] = pk;
    }
    __syncthreads();
    #pragma unroll
    for (int j = 0; j < 2; ++j) {
        const int chunk = t + 256 * j;      // 0..511
        const int l  = chunk >> 3;
        const int ck = chunk & 7;
        u16x8 o;
        #pragma unroll
        for (int i = 0; i < 8; ++i) o[i] = Tr[ck * 8 + i][l];
        *(u16x8*)&xT[((size_t)(b * NL + l0 + l)) * NC + c0 + ck * 8] = o;
    }
}

// ---------------------------------------------------------------------------
// Kernel 1: QKV projection via MFMA. Compute path verbatim from verified
// state; mat==2 (V) epilogue rewritten: stage the [256 c][64 l] tile into
// LDS (reusing XT/WC, dead after the last MFMA) and store coalesced u16x8
// rows, replacing 16K scattered 2-byte global stores per block.
// ---------------------------------------------------------------------------
__global__ __launch_bounds__(256, 2) void qkv_mfma(
    const unsigned short* __restrict__ xT,
    const unsigned short* __restrict__ Wbf,
    const float* __restrict__ bq, const float* __restrict__ bk,
    const float* __restrict__ bv,
    unsigned short* __restrict__ qT, unsigned short* __restrict__ kT,
    unsigned short* __restrict__ vo)
{
    const int raw = blockIdx.x;
    const int b   = raw & 7;          // XCD-pinned batch
    const int rem = raw >> 3;         // 0..95
    const int mat = rem >> 5;         // 0..2
    const int lt0 = (rem & 31) * 64;
    const int t    = threadIdx.x;
    const int w    = t >> 6;
    const int lane = t & 63;
    const int ln15 = lane & 15;
    const int quad = lane >> 4;

    __shared__ __align__(16) char qsmem[65536];
    unsigned short* XT = (unsigned short*)qsmem;             // [l][c] swz, 32 KB
    unsigned short* WC = (unsigned short*)(qsmem + 32768);   // [o][c-chunk] swz, 32 KB
    unsigned short (*Vst)[68] = (unsigned short(*)[68])qsmem; // mat==2 epilogue alias

    const unsigned short* Wm = Wbf + mat * 65536;
    const float* bias = (mat == 0) ? bq : (mat == 1) ? bk : bv;

    float bvals[4][4];
    #pragma unroll
    for (int ot = 0; ot < 4; ++ot)
        #pragma unroll
        for (int r = 0; r < 4; ++r)
            bvals[ot][r] = bias[w * 64 + ot * 16 + quad * 4 + r];

    #pragma unroll
    for (int s = 0; s < 8; ++s) {
        const int il = w * 8 + s;
        const int n  = il * 2 + (lane >> 5);
        const int p  = lane & 31;
        const int g  = p ^ (n & 15);
        const unsigned short* gp = &xT[((size_t)(b * NL + lt0 + n)) * NC + g * 8];
        __builtin_amdgcn_global_load_lds(
            (const __attribute__((address_space(1))) unsigned int*)gp,
            (__attribute__((address_space(3))) unsigned int*)&XT[il * 512],
            16, 0, 0);
    }

    f32x4 acc[4][4];
    #pragma unroll
    for (int i = 0; i < 4; ++i)
        #pragma unroll
        for (int j = 0; j < 4; ++j) acc[i][j] = f32x4{0.f, 0.f, 0.f, 0.f};

    for (int k0 = 0; k0 < 4; ++k0) {
        if (k0) __syncthreads();
        #pragma unroll
        for (int s = 0; s < 8; ++s) {
            const int il = w * 8 + s;
            const int o  = il * 8 + (lane >> 3);
            const int p  = lane & 7;
            const int g  = p ^ (o & 7);
            const unsigned short* gp = &Wm[(size_t)o * NC + k0 * 64 + g * 8];
            __builtin_amdgcn_global_load_lds(
                (const __attribute__((address_space(1))) unsigned int*)gp,
                (__attribute__((address_space(3))) unsigned int*)&WC[il * 512],
                16, 0, 0);
        }
        __syncthreads();

        #pragma unroll
        for (int ks = 0; ks < 2; ++ks) {
            bf16x8 xf[4];
            #pragma unroll
            for (int lt = 0; lt < 4; ++lt) {
                const int l  = lt * 16 + ln15;
                const int kc = k0 * 8 + ks * 4 + quad;
                const int pp = kc ^ (l & 15);
                xf[lt] = __builtin_bit_cast(bf16x8, *(const u32x4*)&XT[l * 256 + pp * 8]);
            }
            #pragma unroll
            for (int ot = 0; ot < 4; ++ot) {
                const int o  = w * 64 + ot * 16 + ln15;
                const int pp = (ks * 4 + quad) ^ (o & 7);
                bf16x8 wf = __builtin_bit_cast(bf16x8, *(const u32x4*)&WC[o * 64 + pp * 8]);
                #pragma unroll
                for (int lt = 0; lt < 4; ++lt)
                    acc[ot][lt] = __builtin_amdgcn_mfma_f32_16x16x32_bf16(
                                      wf, xf[lt], acc[ot][lt], 0, 0, 0);
            }
        }
    }

    if (mat < 2) {
        unsigned short* out = (mat == 0) ? qT : kT;
        #pragma unroll
        for (int ot = 0; ot < 4; ++ot) {
            const int o_base = w * 64 + ot * 16 + quad * 4;
            #pragma unroll
            for (int lt = 0; lt < 4; ++lt) {
                const int l = lt0 + lt * 16 + ln15;
                u16x4 pk;
                #pragma unroll
                for (int r = 0; r < 4; ++r)
                    pk[r] = f2b(acc[ot][lt][r] + bvals[ot][r]);
                *(u16x4*)&out[((size_t)(b * NL + l)) * NC + o_base] = pk;
            }
        }
    } else {
        // ---- V: LDS transpose-stage, then coalesced u16x8 stores ----
        __syncthreads();   // all waves done reading XT/WC
        #pragma unroll
        for (int ot = 0; ot < 4; ++ot)
            #pragma unroll
            for (int lt = 0; lt < 4; ++lt) {
                #pragma unroll
                for (int r = 0; r < 4; ++r) {
                    const int o = w * 64 + ot * 16 + quad * 4 + r;
                    Vst[o][lt * 16 + ln15] = f2b(acc[ot][lt][r] + bvals[ot][r]);
                }
            }
        __syncthreads();
        #pragma unroll
        for (int p = 0; p < 8; ++p) {
            const int row = (t >> 3) + 32 * p;     // channel 0..255
            const int col = (t & 7) * 8;           // l offset 0..56
            u16x8 val = *(const u16x8*)&Vst[row][col];
            *(u16x8*)&vo[((size_t)(b * NC + row)) * NL + lt0 + col] = val;
        }
    }
}

// ---------------------------------------------------------------------------
// Kernel 2: MFMA flash attention + residual — VERBATIM from the verified
// R5 state (153.6 us total / 62.2 us attn, passed). grid 256, block 1024 =
// 16 waves (qg 0..3 x kg 0..3), 4 waves/SIMD. P double-buffered; each
// barrier region computes QK(t) -> P[t&1] and PV(t-1) <- P[(t-1)&1]; one
// full __syncthreads per tile; staging split-schedule K(t+1)/V(t).
// ---------------------------------------------------------------------------
__global__ __launch_bounds__(1024, 4) void attn_kernel(
    const unsigned short* __restrict__ qT,
    const unsigned short* __restrict__ kT,
    const unsigned short* __restrict__ v,
    const float* __restrict__ x,
    float* __restrict__ out)
{
    const int raw  = blockIdx.x;
    const int b    = raw & 7;         // XCD-pinned batch
    const int l0   = (raw >> 3) * 64;
    const int t    = threadIdx.x;
    const int w    = t >> 6;          // 0..15
    const int lane = t & 63;
    const int ln15 = lane & 15;
    const int quad = lane >> 4;
    const int qg   = w & 3;           // query group (16 rows)
    const int kg   = w >> 2;          // key quarter (QK) / channel quarter (PV)

    __shared__ __align__(16) char smem[147456];
    unsigned short* Kb0 = (unsigned short*)smem;             // 32 KB
    unsigned short* Vb0 = (unsigned short*)(smem + 32768);   // 32 KB
    unsigned short* Kb1 = (unsigned short*)(smem + 65536);   // 32 KB
    unsigned short* Vb1 = (unsigned short*)(smem + 98304);   // 32 KB
    char* P0 = smem + 131072;                                //  8 KB [64q][64k] swz
    char* P1 = smem + 139264;                                //  8 KB
    float (*buf)[68] = (float(*)[68])smem;                   // epilogue alias 69.6 KB

    // ---- Q fragments resident: rows l0 + qg*16 + ln15 (B-operand layout) ----
    bf16x8 qf[8];
    {
        const size_t qrow = ((size_t)b * NL + l0 + qg * 16 + ln15) * NC;
        #pragma unroll
        for (int kt = 0; kt < 8; ++kt)
            qf[kt] = __builtin_bit_cast(bf16x8,
                        *(const u32x4*)&qT[qrow + kt * 32 + quad * 8]);
    }

    f32x4 ctx[4];
    #pragma unroll
    for (int i = 0; i < 4; ++i) ctx[i] = f32x4{0.f, 0.f, 0.f, 0.f};
    f32x4 dacc = f32x4{0.f, 0.f, 0.f, 0.f};

    const u16x8 ones_u = {0x3F80, 0x3F80, 0x3F80, 0x3F80,
                          0x3F80, 0x3F80, 0x3F80, 0x3F80};
    const bf16x8 onesf = __builtin_bit_cast(bf16x8, ones_u);

    auto stageK = [&](int mt, unsigned short* Kd) {
        const int m0 = mt * 64;
        #pragma unroll
        for (int s = 0; s < 2; ++s) {
            const int il = w * 2 + s;
            const int n  = il * 2 + (lane >> 5);
            const int g  = (lane & 31) ^ (n & 15);
            const unsigned short* gp = &kT[((size_t)b * NL + m0 + n) * NC + g * 8];
            __builtin_amdgcn_global_load_lds(
                (const __attribute__((address_space(1))) unsigned int*)gp,
                (__attribute__((address_space(3))) unsigned int*)&Kd[il * 512],
                16, 0, 0);
        }
    };
    auto stageV = [&](int mt, unsigned short* Vd) {
        const int m0 = mt * 64;
        #pragma unroll
        for (int s = 0; s < 2; ++s) {
            const int il = w * 2 + s;
            const int c  = il * 8 + (lane >> 3);
            const int g  = (lane & 7) ^ (c & 7);
            const unsigned short* gp = &v[((size_t)(b * NC + c)) * NL + m0 + g * 8];
            __builtin_amdgcn_global_load_lds(
                (const __attribute__((address_space(1))) unsigned int*)gp,
                (__attribute__((address_space(3))) unsigned int*)&Vd[il * 512],
                16, 0, 0);
        }
    };

    const int q    = qg * 16 + ln15;           // this lane's q row
    const int pwof = q * 128 + (((kg * 32) + quad * 8) ^ ((q & 7) << 4));
    int prof[2];
    #pragma unroll
    for (int jw = 0; jw < 2; ++jw)
        prof[jw] = q * 128 + ((jw * 64 + quad * 16) ^ ((q & 7) << 4));

    stageK(0, Kb0);
    __syncthreads();   // K(0) ready

    for (int mt = 0; mt <= 32; ++mt) {
        // ---- issue staging for this region (K one tile ahead, V current) ----
        if (mt < 31) stageK(mt + 1, (mt & 1) ? Kb0 : Kb1);
        if (mt < 32) stageV(mt, (mt & 1) ? Vb1 : Vb0);

        // ---- QK(mt): swapped MFMA, A=K rows (16 keys of quarter kg),
        //      B=Q resident. Lane -> P[key=kg*16+quad*4+r][q]. Two
        //      accumulators halve the dependent-chain depth. ----
        f32x4 sacc0 = f32x4{0.f, 0.f, 0.f, 0.f};
        f32x4 sacc1 = f32x4{0.f, 0.f, 0.f, 0.f};
        if (mt < 32) {
            const unsigned short* Kd = (mt & 1) ? Kb1 : Kb0;
            const int n = kg * 16 + ln15;      // key row in Kd
            #pragma unroll
            for (int kt = 0; kt < 8; kt += 2) {
                const int p0 = (kt * 4 + quad) ^ (n & 15);
                const int p1 = ((kt + 1) * 4 + quad) ^ (n & 15);
                bf16x8 kf0 = __builtin_bit_cast(bf16x8,
                               *(const u32x4*)&Kd[n * 256 + p0 * 8]);
                bf16x8 kf1 = __builtin_bit_cast(bf16x8,
                               *(const u32x4*)&Kd[n * 256 + p1 * 8]);
                sacc0 = __builtin_amdgcn_mfma_f32_16x16x32_bf16(
                            kf0, qf[kt], sacc0, 0, 0, 0);
                sacc1 = __builtin_amdgcn_mfma_f32_16x16x32_bf16(
                            kf1, qf[kt + 1], sacc1, 0, 0, 0);
            }
        }

        // ---- PV(mt-1): independent of QK(mt); overlaps it ----
        if (mt > 0) {
            const char* Pr = ((mt - 1) & 1) ? P1 : P0;
            const unsigned short* Vd = ((mt - 1) & 1) ? Vb1 : Vb0;
            bf16x8 pa[2];
            #pragma unroll
            for (int jw = 0; jw < 2; ++jw)
                pa[jw] = __builtin_bit_cast(bf16x8, *(const u32x4*)(Pr + prof[jw]));
            dacc = __builtin_amdgcn_mfma_f32_16x16x32_bf16(pa[0], onesf, dacc, 0, 0, 0);
            dacc = __builtin_amdgcn_mfma_f32_16x16x32_bf16(pa[1], onesf, dacc, 0, 0, 0);
            #pragma unroll
            for (int ct = 0; ct < 4; ++ct) {
                const int c = kg * 64 + ct * 16 + ln15;
                #pragma unroll
                for (int jw = 0; jw < 2; ++jw) {
                    const int p = (jw * 4 + quad) ^ (c & 7);
                    bf16x8 vb = __builtin_bit_cast(bf16x8,
                                  *(const u32x4*)&Vd[c * 64 + p * 8]);
                    ctx[ct] = __builtin_amdgcn_mfma_f32_16x16x32_bf16(
                                  pa[jw], vb, ctx[ct], 0, 0, 0);
                }
            }
        }

        // ---- exp + P store for tile mt (after PV so sacc chain has drained) ----
        if (mt < 32) {
            char* Pw = (mt & 1) ? P1 : P0;
            float e0 = __expf((sacc0[0] + sacc1[0]) * SCALE);
            float e1 = __expf((sacc0[1] + sacc1[1]) * SCALE);
            float e2 = __expf((sacc0[2] + sacc1[2]) * SCALE);
            float e3 = __expf((sacc0[3] + sacc1[3]) * SCALE);
            unsigned int d0 = (unsigned int)f2b(e0) | ((unsigned int)f2b(e1) << 16);
            unsigned int d1 = (unsigned int)f2b(e2) | ((unsigned int)f2b(e3) << 16);
            *(u32x2*)(Pw + pwof) = u32x2{d0, d1};
        }

        __syncthreads();   // region end: P visible, staging landed, bufs safe
    }

    // ---- epilogue: in-register normalize, stage to LDS, residual, store ----
    {
        float rinv[4];
        #pragma unroll
        for (int r = 0; r < 4; ++r) rinv[r] = 1.0f / dacc[r];
        #pragma unroll
        for (int ct = 0; ct < 4; ++ct) {
            const int c = kg * 64 + ct * 16 + ln15;
            #pragma unroll
            for (int r = 0; r < 4; ++r)
                buf[c][qg * 16 + quad * 4 + r] = ctx[ct][r] * rinv[r];
        }
    }
    __syncthreads();

    #pragma unroll
    for (int p = 0; p < 4; ++p) {
        const int f  = t + 1024 * p;      // 0..4095
        const int c  = f >> 4;
        const int lg = (f & 15) * 4;
        const size_t idx = ((size_t)(b * NC + c)) * NL + l0 + lg;
        float4 xv = *(const float4*)&x[idx];
        float4 cv = *(const float4*)&buf[c][lg];
        float4 o = make_float4(cv.x + xv.x, cv.y + xv.y, cv.z + xv.z, cv.w + xv.w);
        *(float4*)&out[idx] = o;
    }
}

// ---------------------------------------------------------------------------
extern "C" void kernel_launch(void* const* d_in, const int* in_sizes, int n_in,
                              void* d_out, int out_size, void* d_ws, size_t ws_size,
                              hipStream_t stream) {
    const float* x  = (const float*)d_in[0];
    const float* Wq = (const float*)d_in[1];
    const float* bq = (const float*)d_in[2];
    const float* Wk = (const float*)d_in[3];
    const float* bk = (const float*)d_in[4];
    const float* Wv = (const float*)d_in[5];
    const float* bv = (const float*)d_in[6];
    float* out = (float*)d_out;

    const size_t plane = (size_t)NB * NC * NL;       // 4.19M elems
    unsigned short* qT  = (unsigned short*)d_ws;
    unsigned short* kT  = qT + plane;
    unsigned short* v   = kT + plane;
    unsigned short* xT  = v + plane;
    unsigned short* Wbf = xT + plane;                // 3*65536 elems

    prep_kernel<<<1216, 256, 0, stream>>>(x, xT, Wq, Wk, Wv, Wbf);

    qkv_mfma<<<768, 256, 0, stream>>>(xT, Wbf, bq, bk, bv, qT, kT, v);

    attn_kernel<<<256, 1024, 0, stream>>>(qT, kT, v, x, out);
}

// Round 9
// 149.723 us; speedup vs baseline: 1.4691x; 1.0017x over previous
//
#include <hip/hip_runtime.h>

#define NB 8
#define NC 256
#define NL 2048
#define SCALE 0.0625f   // C^-0.5 = 1/16

typedef __attribute__((ext_vector_type(8))) __bf16 bf16x8;
typedef __attribute__((ext_vector_type(4))) float f32x4;
typedef __attribute__((ext_vector_type(4))) unsigned int u32x4;
typedef __attribute__((ext_vector_type(2))) unsigned int u32x2;
typedef __attribute__((ext_vector_type(4))) unsigned short u16x4;
typedef __attribute__((ext_vector_type(8))) unsigned short u16x8;

// round-to-nearest-even fp32 -> bf16 bits
static __device__ __forceinline__ unsigned short f2b(float f) {
    unsigned int u = __builtin_bit_cast(unsigned int, f);
    u += 0x7fffu + ((u >> 16) & 1u);
    return (unsigned short)(u >> 16);
}

// ---------------------------------------------------------------------------
// Prep: Wq/Wk/Wv fp32 -> bf16, concatenated [3][256][256]. (tiny)
// ---------------------------------------------------------------------------
__global__ void wconv_kernel(const float* __restrict__ Wq,
                             const float* __restrict__ Wk,
                             const float* __restrict__ Wv,
                             unsigned short* __restrict__ Wbf)
{
    const int base = (blockIdx.x * 256 + threadIdx.x) * 4;
    const int mat  = base >> 16;
    const int off  = base & 65535;
    const float* W = (mat == 0) ? Wq : (mat == 1) ? Wk : Wv;
    float4 w = *(const float4*)&W[off];
    u16x4 p = {f2b(w.x), f2b(w.y), f2b(w.z), f2b(w.w)};
    *(u16x4*)&Wbf[base] = p;
}

// ---------------------------------------------------------------------------
// Kernel 1: QKV projection via MFMA, now FUSED with the x-transpose:
// each block reads its x [256 c][64 l] fp32 tile directly (L2-resident,
// XCD-pinned batch), transposes via the verified Tr pattern, and writes
// XT [l][c] bf16 with the same XOR-swizzle relation the MFMA reader uses
// (slot s of row l holds granule s ^ (l&15)). Eliminates the xT pass.
// Compute path + V coalesced epilogue verbatim from the verified R8 state.
// ---------------------------------------------------------------------------
__global__ __launch_bounds__(256, 2) void qkv_mfma(
    const float* __restrict__ x,
    const unsigned short* __restrict__ Wbf,
    const float* __restrict__ bq, const float* __restrict__ bk,
    const float* __restrict__ bv,
    unsigned short* __restrict__ qT, unsigned short* __restrict__ kT,
    unsigned short* __restrict__ vo)
{
    const int raw = blockIdx.x;
    const int b   = raw & 7;          // XCD-pinned batch
    const int rem = raw >> 3;         // 0..95
    const int mat = rem >> 5;         // 0..2
    const int lt0 = (rem & 31) * 64;
    const int t    = threadIdx.x;
    const int w    = t >> 6;
    const int lane = t & 63;
    const int ln15 = lane & 15;
    const int quad = lane >> 4;

    __shared__ __align__(16) char qsmem[74240];
    unsigned short* XT = (unsigned short*)qsmem;             // [l][c] swz, 32 KB
    unsigned short* WC = (unsigned short*)(qsmem + 32768);   // [o][c-chunk] swz, 32 KB
    unsigned short (*Tr)[68] = (unsigned short(*)[68])(qsmem + 65536); // 8.7 KB
    unsigned short (*Vst)[68] = (unsigned short(*)[68])qsmem; // mat==2 epilogue alias

    const unsigned short* Wm = Wbf + mat * 65536;
    const float* bias = (mat == 0) ? bq : (mat == 1) ? bk : bv;

    float bvals[4][4];
    #pragma unroll
    for (int ot = 0; ot < 4; ++ot)
        #pragma unroll
        for (int r = 0; r < 4; ++r)
            bvals[ot][r] = bias[w * 64 + ot * 16 + quad * 4 + r];

    // ---- in-kernel x[c][l] fp32 -> XT[l][c] bf16 (swizzled), 4 subtiles ----
    for (int cs = 0; cs < 4; ++cs) {
        const int c0 = cs * 64;
        #pragma unroll
        for (int p = 0; p < 4; ++p) {
            const int c  = p * 16 + (t >> 4);      // 0..63 within subtile
            const int lg = t & 15;
            float4 xv = *(const float4*)&x[((size_t)(b * NC + c0 + c)) * NL + lt0 + lg * 4];
            u16x4 pk = {f2b(xv.x), f2b(xv.y), f2b(xv.z), f2b(xv.w)};
            *(u16x4*)&Tr[c][lg * 4] = pk;
        }
        __syncthreads();
        #pragma unroll
        for (int j = 0; j < 2; ++j) {
            const int chunk = t + 256 * j;      // 0..511
            const int l  = chunk >> 3;          // 0..63
            const int ck = chunk & 7;           // granule within subtile
            u16x8 o;
            #pragma unroll
            for (int i = 0; i < 8; ++i) o[i] = Tr[ck * 8 + i][l];
            const int g = (cs * 8 + ck) ^ (l & 15);   // swizzled slot
            *(u16x8*)&XT[l * 256 + g * 8] = o;
        }
        __syncthreads();
    }

    f32x4 acc[4][4];
    #pragma unroll
    for (int i = 0; i < 4; ++i)
        #pragma unroll
        for (int j = 0; j < 4; ++j) acc[i][j] = f32x4{0.f, 0.f, 0.f, 0.f};

    for (int k0 = 0; k0 < 4; ++k0) {
        if (k0) __syncthreads();
        #pragma unroll
        for (int s = 0; s < 8; ++s) {
            const int il = w * 8 + s;
            const int o  = il * 8 + (lane >> 3);
            const int p  = lane & 7;
            const int g  = p ^ (o & 7);
            const unsigned short* gp = &Wm[(size_t)o * NC + k0 * 64 + g * 8];
            __builtin_amdgcn_global_load_lds(
                (const __attribute__((address_space(1))) unsigned int*)gp,
                (__attribute__((address_space(3))) unsigned int*)&WC[il * 512],
                16, 0, 0);
        }
        __syncthreads();

        #pragma unroll
        for (int ks = 0; ks < 2; ++ks) {
            bf16x8 xf[4];
            #pragma unroll
            for (int lt = 0; lt < 4; ++lt) {
                const int l  = lt * 16 + ln15;
                const int kc = k0 * 8 + ks * 4 + quad;
                const int pp = kc ^ (l & 15);
                xf[lt] = __builtin_bit_cast(bf16x8, *(const u32x4*)&XT[l * 256 + pp * 8]);
            }
            #pragma unroll
            for (int ot = 0; ot < 4; ++ot) {
                const int o  = w * 64 + ot * 16 + ln15;
                const int pp = (ks * 4 + quad) ^ (o & 7);
                bf16x8 wf = __builtin_bit_cast(bf16x8, *(const u32x4*)&WC[o * 64 + pp * 8]);
                #pragma unroll
                for (int lt = 0; lt < 4; ++lt)
                    acc[ot][lt] = __builtin_amdgcn_mfma_f32_16x16x32_bf16(
                                      wf, xf[lt], acc[ot][lt], 0, 0, 0);
            }
        }
    }

    if (mat < 2) {
        unsigned short* out = (mat == 0) ? qT : kT;
        #pragma unroll
        for (int ot = 0; ot < 4; ++ot) {
            const int o_base = w * 64 + ot * 16 + quad * 4;
            #pragma unroll
            for (int lt = 0; lt < 4; ++lt) {
                const int l = lt0 + lt * 16 + ln15;
                u16x4 pk;
                #pragma unroll
                for (int r = 0; r < 4; ++r)
                    pk[r] = f2b(acc[ot][lt][r] + bvals[ot][r]);
                *(u16x4*)&out[((size_t)(b * NL + l)) * NC + o_base] = pk;
            }
        }
    } else {
        // ---- V: LDS transpose-stage, then coalesced u16x8 stores ----
        __syncthreads();   // all waves done reading XT/WC
        #pragma unroll
        for (int ot = 0; ot < 4; ++ot)
            #pragma unroll
            for (int lt = 0; lt < 4; ++lt) {
                #pragma unroll
                for (int r = 0; r < 4; ++r) {
                    const int o = w * 64 + ot * 16 + quad * 4 + r;
                    Vst[o][lt * 16 + ln15] = f2b(acc[ot][lt][r] + bvals[ot][r]);
                }
            }
        __syncthreads();
        #pragma unroll
        for (int p = 0; p < 8; ++p) {
            const int row = (t >> 3) + 32 * p;     // channel 0..255
            const int col = (t & 7) * 8;           // l offset 0..56
            u16x8 val = *(const u16x8*)&Vst[row][col];
            *(u16x8*)&vo[((size_t)(b * NC + row)) * NL + lt0 + col] = val;
        }
    }
}

// ---------------------------------------------------------------------------
// Kernel 2: MFMA flash attention + residual — VERBATIM from the verified
// R8 state (149.98 us total / 59.3 us attn, passed). grid 256, block 1024 =
// 16 waves (qg 0..3 x kg 0..3), 4 waves/SIMD. P double-buffered; each
// barrier region computes QK(t) -> P[t&1] and PV(t-1) <- P[(t-1)&1]; one
// full __syncthreads per tile; staging split-schedule K(t+1)/V(t).
// ---------------------------------------------------------------------------
__global__ __launch_bounds__(1024, 4) void attn_kernel(
    const unsigned short* __restrict__ qT,
    const unsigned short* __restrict__ kT,
    const unsigned short* __restrict__ v,
    const float* __restrict__ x,
    float* __restrict__ out)
{
    const int raw  = blockIdx.x;
    const int b    = raw & 7;         // XCD-pinned batch
    const int l0   = (raw >> 3) * 64;
    const int t    = threadIdx.x;
    const int w    = t >> 6;          // 0..15
    const int lane = t & 63;
    const int ln15 = lane & 15;
    const int quad = lane >> 4;
    const int qg   = w & 3;           // query group (16 rows)
    const int kg   = w >> 2;          // key quarter (QK) / channel quarter (PV)

    __shared__ __align__(16) char smem[147456];
    unsigned short* Kb0 = (unsigned short*)smem;             // 32 KB
    unsigned short* Vb0 = (unsigned short*)(smem + 32768);   // 32 KB
    unsigned short* Kb1 = (unsigned short*)(smem + 65536);   // 32 KB
    unsigned short* Vb1 = (unsigned short*)(smem + 98304);   // 32 KB
    char* P0 = smem + 131072;                                //  8 KB [64q][64k] swz
    char* P1 = smem + 139264;                                //  8 KB
    float (*buf)[68] = (float(*)[68])smem;                   // epilogue alias 69.6 KB

    // ---- Q fragments resident: rows l0 + qg*16 + ln15 (B-operand layout) ----
    bf16x8 qf[8];
    {
        const size_t qrow = ((size_t)b * NL + l0 + qg * 16 + ln15) * NC;
        #pragma unroll
        for (int kt = 0; kt < 8; ++kt)
            qf[kt] = __builtin_bit_cast(bf16x8,
                        *(const u32x4*)&qT[qrow + kt * 32 + quad * 8]);
    }

    f32x4 ctx[4];
    #pragma unroll
    for (int i = 0; i < 4; ++i) ctx[i] = f32x4{0.f, 0.f, 0.f, 0.f};
    f32x4 dacc = f32x4{0.f, 0.f, 0.f, 0.f};

    const u16x8 ones_u = {0x3F80, 0x3F80, 0x3F80, 0x3F80,
                          0x3F80, 0x3F80, 0x3F80, 0x3F80};
    const bf16x8 onesf = __builtin_bit_cast(bf16x8, ones_u);

    auto stageK = [&](int mt, unsigned short* Kd) {
        const int m0 = mt * 64;
        #pragma unroll
        for (int s = 0; s < 2; ++s) {
            const int il = w * 2 + s;
            const int n  = il * 2 + (lane >> 5);
            const int g  = (lane & 31) ^ (n & 15);
            const unsigned short* gp = &kT[((size_t)b * NL + m0 + n) * NC + g * 8];
            __builtin_amdgcn_global_load_lds(
                (const __attribute__((address_space(1))) unsigned int*)gp,
                (__attribute__((address_space(3))) unsigned int*)&Kd[il * 512],
                16, 0, 0);
        }
    };
    auto stageV = [&](int mt, unsigned short* Vd) {
        const int m0 = mt * 64;
        #pragma unroll
        for (int s = 0; s < 2; ++s) {
            const int il = w * 2 + s;
            const int c  = il * 8 + (lane >> 3);
            const int g  = (lane & 7) ^ (c & 7);
            const unsigned short* gp = &v[((size_t)(b * NC + c)) * NL + m0 + g * 8];
            __builtin_amdgcn_global_load_lds(
                (const __attribute__((address_space(1))) unsigned int*)gp,
                (__attribute__((address_space(3))) unsigned int*)&Vd[il * 512],
                16, 0, 0);
        }
    };

    const int q    = qg * 16 + ln15;           // this lane's q row
    const int pwof = q * 128 + (((kg * 32) + quad * 8) ^ ((q & 7) << 4));
    int prof[2];
    #pragma unroll
    for (int jw = 0; jw < 2; ++jw)
        prof[jw] = q * 128 + ((jw * 64 + quad * 16) ^ ((q & 7) << 4));

    stageK(0, Kb0);
    __syncthreads();   // K(0) ready

    for (int mt = 0; mt <= 32; ++mt) {
        // ---- issue staging for this region (K one tile ahead, V current) ----
        if (mt < 31) stageK(mt + 1, (mt & 1) ? Kb0 : Kb1);
        if (mt < 32) stageV(mt, (mt & 1) ? Vb1 : Vb0);

        // ---- QK(mt): swapped MFMA, A=K rows (16 keys of quarter kg),
        //      B=Q resident. Lane -> P[key=kg*16+quad*4+r][q]. Two
        //      accumulators halve the dependent-chain depth. ----
        f32x4 sacc0 = f32x4{0.f, 0.f, 0.f, 0.f};
        f32x4 sacc1 = f32x4{0.f, 0.f, 0.f, 0.f};
        if (mt < 32) {
            const unsigned short* Kd = (mt & 1) ? Kb1 : Kb0;
            const int n = kg * 16 + ln15;      // key row in Kd
            #pragma unroll
            for (int kt = 0; kt < 8; kt += 2) {
                const int p0 = (kt * 4 + quad) ^ (n & 15);
                const int p1 = ((kt + 1) * 4 + quad) ^ (n & 15);
                bf16x8 kf0 = __builtin_bit_cast(bf16x8,
                               *(const u32x4*)&Kd[n * 256 + p0 * 8]);
                bf16x8 kf1 = __builtin_bit_cast(bf16x8,
                               *(const u32x4*)&Kd[n * 256 + p1 * 8]);
                sacc0 = __builtin_amdgcn_mfma_f32_16x16x32_bf16(
                            kf0, qf[kt], sacc0, 0, 0, 0);
                sacc1 = __builtin_amdgcn_mfma_f32_16x16x32_bf16(
                            kf1, qf[kt + 1], sacc1, 0, 0, 0);
            }
        }

        // ---- PV(mt-1): independent of QK(mt); overlaps it ----
        if (mt > 0) {
            const char* Pr = ((mt - 1) & 1) ? P1 : P0;
            const unsigned short* Vd = ((mt - 1) & 1) ? Vb1 : Vb0;
            bf16x8 pa[2];
            #pragma unroll
            for (int jw = 0; jw < 2; ++jw)
                pa[jw] = __builtin_bit_cast(bf16x8, *(const u32x4*)(Pr + prof[jw]));
            dacc = __builtin_amdgcn_mfma_f32_16x16x32_bf16(pa[0], onesf, dacc, 0, 0, 0);
            dacc = __builtin_amdgcn_mfma_f32_16x16x32_bf16(pa[1], onesf, dacc, 0, 0, 0);
            #pragma unroll
            for (int ct = 0; ct < 4; ++ct) {
                const int c = kg * 64 + ct * 16 + ln15;
                #pragma unroll
                for (int jw = 0; jw < 2; ++jw) {
                    const int p = (jw * 4 + quad) ^ (c & 7);
                    bf16x8 vb = __builtin_bit_cast(bf16x8,
                                  *(const u32x4*)&Vd[c * 64 + p * 8]);
                    ctx[ct] = __builtin_amdgcn_mfma_f32_16x16x32_bf16(
                                  pa[jw], vb, ctx[ct], 0, 0, 0);
                }
            }
        }

        // ---- exp + P store for tile mt (after PV so sacc chain has drained) ----
        if (mt < 32) {
            char* Pw = (mt & 1) ? P1 : P0;
            float e0 = __expf((sacc0[0] + sacc1[0]) * SCALE);
            float e1 = __expf((sacc0[1] + sacc1[1]) * SCALE);
            float e2 = __expf((sacc0[2] + sacc1[2]) * SCALE);
            float e3 = __expf((sacc0[3] + sacc1[3]) * SCALE);
            unsigned int d0 = (unsigned int)f2b(e0) | ((unsigned int)f2b(e1) << 16);
            unsigned int d1 = (unsigned int)f2b(e2) | ((unsigned int)f2b(e3) << 16);
            *(u32x2*)(Pw + pwof) = u32x2{d0, d1};
        }

        __syncthreads();   // region end: P visible, staging landed, bufs safe
    }

    // ---- epilogue: in-register normalize, stage to LDS, residual, store ----
    {
        float rinv[4];
        #pragma unroll
        for (int r = 0; r < 4; ++r) rinv[r] = 1.0f / dacc[r];
        #pragma unroll
        for (int ct = 0; ct < 4; ++ct) {
            const int c = kg * 64 + ct * 16 + ln15;
            #pragma unroll
            for (int r = 0; r < 4; ++r)
                buf[c][qg * 16 + quad * 4 + r] = ctx[ct][r] * rinv[r];
        }
    }
    __syncthreads();

    #pragma unroll
    for (int p = 0; p < 4; ++p) {
        const int f  = t + 1024 * p;      // 0..4095
        const int c  = f >> 4;
        const int lg = (f & 15) * 4;
        const size_t idx = ((size_t)(b * NC + c)) * NL + l0 + lg;
        float4 xv = *(const float4*)&x[idx];
        float4 cv = *(const float4*)&buf[c][lg];
        float4 o = make_float4(cv.x + xv.x, cv.y + xv.y, cv.z + xv.z, cv.w + xv.w);
        *(float4*)&out[idx] = o;
    }
}

// ---------------------------------------------------------------------------
extern "C" void kernel_launch(void* const* d_in, const int* in_sizes, int n_in,
                              void* d_out, int out_size, void* d_ws, size_t ws_size,
                              hipStream_t stream) {
    const float* x  = (const float*)d_in[0];
    const float* Wq = (const float*)d_in[1];
    const float* bq = (const float*)d_in[2];
    const float* Wk = (const float*)d_in[3];
    const float* bk = (const float*)d_in[4];
    const float* Wv = (const float*)d_in[5];
    const float* bv = (const float*)d_in[6];
    float* out = (float*)d_out;

    const size_t plane = (size_t)NB * NC * NL;       // 4.19M elems
    unsigned short* qT  = (unsigned short*)d_ws;
    unsigned short* kT  = qT + plane;
    unsigned short* v   = kT + plane;
    unsigned short* Wbf = v + plane;                 // 3*65536 elems

    wconv_kernel<<<192, 256, 0, stream>>>(Wq, Wk, Wv, Wbf);

    qkv_mfma<<<768, 256, 0, stream>>>(x, Wbf, bq, bk, bv, qT, kT, v);

    attn_kernel<<<256, 1024, 0, stream>>>(qT, kT, v, x, out);
}

// Round 10
// 148.742 us; speedup vs baseline: 1.4787x; 1.0066x over previous
//
#include <hip/hip_runtime.h>

#define NB 8
#define NC 256
#define NL 2048
#define SCALE 0.0625f   // C^-0.5 = 1/16

typedef __attribute__((ext_vector_type(8))) __bf16 bf16x8;
typedef __attribute__((ext_vector_type(4))) float f32x4;
typedef __attribute__((ext_vector_type(4))) unsigned int u32x4;
typedef __attribute__((ext_vector_type(2))) unsigned int u32x2;
typedef __attribute__((ext_vector_type(4))) unsigned short u16x4;
typedef __attribute__((ext_vector_type(8))) unsigned short u16x8;

// round-to-nearest-even fp32 -> bf16 bits
static __device__ __forceinline__ unsigned short f2b(float f) {
    unsigned int u = __builtin_bit_cast(unsigned int, f);
    u += 0x7fffu + ((u >> 16) & 1u);
    return (unsigned short)(u >> 16);
}

// ---------------------------------------------------------------------------
// Prep: Wq/Wk/Wv fp32 -> bf16, concatenated [3][256][256]. (tiny)
// ---------------------------------------------------------------------------
__global__ void wconv_kernel(const float* __restrict__ Wq,
                             const float* __restrict__ Wk,
                             const float* __restrict__ Wv,
                             unsigned short* __restrict__ Wbf)
{
    const int base = (blockIdx.x * 256 + threadIdx.x) * 4;
    const int mat  = base >> 16;
    const int off  = base & 65535;
    const float* W = (mat == 0) ? Wq : (mat == 1) ? Wk : Wv;
    float4 w = *(const float4*)&W[off];
    u16x4 p = {f2b(w.x), f2b(w.y), f2b(w.z), f2b(w.w)};
    *(u16x4*)&Wbf[base] = p;
}

// ---------------------------------------------------------------------------
// Kernel 1: QKV projection via MFMA, fused x-transpose. RE-SHARDED to
// 512-thread / 8-wave blocks: same grid (768), same tile ([256 o][64 l]),
// same 74 KB LDS (2 blocks/CU) -> 16 waves/CU = 4 waves/SIMD (was 2).
// Each wave owns 32 o-rows (acc[2][4]); all swizzle formulas, the MFMA
// body, the Tr transpose pattern and the V coalesced epilogue are the
// verified R9 ones with only the thread/wave re-split.
// ---------------------------------------------------------------------------
__global__ __launch_bounds__(512, 4) void qkv_mfma(
    const float* __restrict__ x,
    const unsigned short* __restrict__ Wbf,
    const float* __restrict__ bq, const float* __restrict__ bk,
    const float* __restrict__ bv,
    unsigned short* __restrict__ qT, unsigned short* __restrict__ kT,
    unsigned short* __restrict__ vo)
{
    const int raw = blockIdx.x;
    const int b   = raw & 7;          // XCD-pinned batch
    const int rem = raw >> 3;         // 0..95
    const int mat = rem >> 5;         // 0..2
    const int lt0 = (rem & 31) * 64;
    const int t    = threadIdx.x;     // 0..511
    const int w    = t >> 6;          // 0..7
    const int lane = t & 63;
    const int ln15 = lane & 15;
    const int quad = lane >> 4;

    __shared__ __align__(16) char qsmem[74240];
    unsigned short* XT = (unsigned short*)qsmem;             // [l][c] swz, 32 KB
    unsigned short* WC = (unsigned short*)(qsmem + 32768);   // [o][c-chunk] swz, 32 KB
    unsigned short (*Tr)[68] = (unsigned short(*)[68])(qsmem + 65536); // 8.7 KB
    unsigned short (*Vst)[68] = (unsigned short(*)[68])qsmem; // mat==2 epilogue alias

    const unsigned short* Wm = Wbf + mat * 65536;
    const float* bias = (mat == 0) ? bq : (mat == 1) ? bk : bv;

    float bvals[2][4];
    #pragma unroll
    for (int ot = 0; ot < 2; ++ot)
        #pragma unroll
        for (int r = 0; r < 4; ++r)
            bvals[ot][r] = bias[w * 32 + ot * 16 + quad * 4 + r];

    // ---- in-kernel x[c][l] fp32 -> XT[l][c] bf16 (swizzled), 4 subtiles ----
    for (int cs = 0; cs < 4; ++cs) {
        const int c0 = cs * 64;
        #pragma unroll
        for (int p = 0; p < 2; ++p) {
            const int c  = p * 32 + (t >> 4);      // 0..63 within subtile
            const int lg = t & 15;
            float4 xv = *(const float4*)&x[((size_t)(b * NC + c0 + c)) * NL + lt0 + lg * 4];
            u16x4 pk = {f2b(xv.x), f2b(xv.y), f2b(xv.z), f2b(xv.w)};
            *(u16x4*)&Tr[c][lg * 4] = pk;
        }
        __syncthreads();
        {
            const int l  = t >> 3;              // 0..63
            const int ck = t & 7;               // granule within subtile
            u16x8 o;
            #pragma unroll
            for (int i = 0; i < 8; ++i) o[i] = Tr[ck * 8 + i][l];
            const int g = (cs * 8 + ck) ^ (l & 15);   // swizzled slot
            *(u16x8*)&XT[l * 256 + g * 8] = o;
        }
        __syncthreads();
    }

    f32x4 acc[2][4];
    #pragma unroll
    for (int i = 0; i < 2; ++i)
        #pragma unroll
        for (int j = 0; j < 4; ++j) acc[i][j] = f32x4{0.f, 0.f, 0.f, 0.f};

    for (int k0 = 0; k0 < 4; ++k0) {
        if (k0) __syncthreads();
        #pragma unroll
        for (int s = 0; s < 4; ++s) {
            const int il = w * 4 + s;             // 0..31
            const int o  = il * 8 + (lane >> 3);
            const int p  = lane & 7;
            const int g  = p ^ (o & 7);
            const unsigned short* gp = &Wm[(size_t)o * NC + k0 * 64 + g * 8];
            __builtin_amdgcn_global_load_lds(
                (const __attribute__((address_space(1))) unsigned int*)gp,
                (__attribute__((address_space(3))) unsigned int*)&WC[il * 512],
                16, 0, 0);
        }
        __syncthreads();

        #pragma unroll
        for (int ks = 0; ks < 2; ++ks) {
            bf16x8 xf[4];
            #pragma unroll
            for (int lt = 0; lt < 4; ++lt) {
                const int l  = lt * 16 + ln15;
                const int kc = k0 * 8 + ks * 4 + quad;
                const int pp = kc ^ (l & 15);
                xf[lt] = __builtin_bit_cast(bf16x8, *(const u32x4*)&XT[l * 256 + pp * 8]);
            }
            #pragma unroll
            for (int ot = 0; ot < 2; ++ot) {
                const int o  = w * 32 + ot * 16 + ln15;
                const int pp = (ks * 4 + quad) ^ (o & 7);
                bf16x8 wf = __builtin_bit_cast(bf16x8, *(const u32x4*)&WC[o * 64 + pp * 8]);
                #pragma unroll
                for (int lt = 0; lt < 4; ++lt)
                    acc[ot][lt] = __builtin_amdgcn_mfma_f32_16x16x32_bf16(
                                      wf, xf[lt], acc[ot][lt], 0, 0, 0);
            }
        }
    }

    if (mat < 2) {
        unsigned short* out = (mat == 0) ? qT : kT;
        #pragma unroll
        for (int ot = 0; ot < 2; ++ot) {
            const int o_base = w * 32 + ot * 16 + quad * 4;
            #pragma unroll
            for (int lt = 0; lt < 4; ++lt) {
                const int l = lt0 + lt * 16 + ln15;
                u16x4 pk;
                #pragma unroll
                for (int r = 0; r < 4; ++r)
                    pk[r] = f2b(acc[ot][lt][r] + bvals[ot][r]);
                *(u16x4*)&out[((size_t)(b * NL + l)) * NC + o_base] = pk;
            }
        }
    } else {
        // ---- V: LDS transpose-stage, then coalesced u16x8 stores ----
        __syncthreads();   // all waves done reading XT/WC
        #pragma unroll
        for (int ot = 0; ot < 2; ++ot)
            #pragma unroll
            for (int lt = 0; lt < 4; ++lt) {
                #pragma unroll
                for (int r = 0; r < 4; ++r) {
                    const int o = w * 32 + ot * 16 + quad * 4 + r;
                    Vst[o][lt * 16 + ln15] = f2b(acc[ot][lt][r] + bvals[ot][r]);
                }
            }
        __syncthreads();
        #pragma unroll
        for (int p = 0; p < 4; ++p) {
            const int row = (t >> 3) + 64 * p;     // channel 0..255
            const int col = (t & 7) * 8;           // l offset 0..56
            u16x8 val = *(const u16x8*)&Vst[row][col];
            *(u16x8*)&vo[((size_t)(b * NC + row)) * NL + lt0 + col] = val;
        }
    }
}

// ---------------------------------------------------------------------------
// Kernel 2: MFMA flash attention + residual — VERBATIM from the verified
// R8/R9 state (~60 us attn, passed). grid 256, block 1024 = 16 waves
// (qg 0..3 x kg 0..3), 4 waves/SIMD. P double-buffered; each barrier region
// computes QK(t) -> P[t&1] and PV(t-1) <- P[(t-1)&1]; one full
// __syncthreads per tile; staging split-schedule K(t+1)/V(t).
// ---------------------------------------------------------------------------
__global__ __launch_bounds__(1024, 4) void attn_kernel(
    const unsigned short* __restrict__ qT,
    const unsigned short* __restrict__ kT,
    const unsigned short* __restrict__ v,
    const float* __restrict__ x,
    float* __restrict__ out)
{
    const int raw  = blockIdx.x;
    const int b    = raw & 7;         // XCD-pinned batch
    const int l0   = (raw >> 3) * 64;
    const int t    = threadIdx.x;
    const int w    = t >> 6;          // 0..15
    const int lane = t & 63;
    const int ln15 = lane & 15;
    const int quad = lane >> 4;
    const int qg   = w & 3;           // query group (16 rows)
    const int kg   = w >> 2;          // key quarter (QK) / channel quarter (PV)

    __shared__ __align__(16) char smem[147456];
    unsigned short* Kb0 = (unsigned short*)smem;             // 32 KB
    unsigned short* Vb0 = (unsigned short*)(smem + 32768);   // 32 KB
    unsigned short* Kb1 = (unsigned short*)(smem + 65536);   // 32 KB
    unsigned short* Vb1 = (unsigned short*)(smem + 98304);   // 32 KB
    char* P0 = smem + 131072;                                //  8 KB [64q][64k] swz
    char* P1 = smem + 139264;                                //  8 KB
    float (*buf)[68] = (float(*)[68])smem;                   // epilogue alias 69.6 KB

    // ---- Q fragments resident: rows l0 + qg*16 + ln15 (B-operand layout) ----
    bf16x8 qf[8];
    {
        const size_t qrow = ((size_t)b * NL + l0 + qg * 16 + ln15) * NC;
        #pragma unroll
        for (int kt = 0; kt < 8; ++kt)
            qf[kt] = __builtin_bit_cast(bf16x8,
                        *(const u32x4*)&qT[qrow + kt * 32 + quad * 8]);
    }

    f32x4 ctx[4];
    #pragma unroll
    for (int i = 0; i < 4; ++i) ctx[i] = f32x4{0.f, 0.f, 0.f, 0.f};
    f32x4 dacc = f32x4{0.f, 0.f, 0.f, 0.f};

    const u16x8 ones_u = {0x3F80, 0x3F80, 0x3F80, 0x3F80,
                          0x3F80, 0x3F80, 0x3F80, 0x3F80};
    const bf16x8 onesf = __builtin_bit_cast(bf16x8, ones_u);

    auto stageK = [&](int mt, unsigned short* Kd) {
        const int m0 = mt * 64;
        #pragma unroll
        for (int s = 0; s < 2; ++s) {
            const int il = w * 2 + s;
            const int n  = il * 2 + (lane >> 5);
            const int g  = (lane & 31) ^ (n & 15);
            const unsigned short* gp = &kT[((size_t)b * NL + m0 + n) * NC + g * 8];
            __builtin_amdgcn_global_load_lds(
                (const __attribute__((address_space(1))) unsigned int*)gp,
                (__attribute__((address_space(3))) unsigned int*)&Kd[il * 512],
                16, 0, 0);
        }
    };
    auto stageV = [&](int mt, unsigned short* Vd) {
        const int m0 = mt * 64;
        #pragma unroll
        for (int s = 0; s < 2; ++s) {
            const int il = w * 2 + s;
            const int c  = il * 8 + (lane >> 3);
            const int g  = (lane & 7) ^ (c & 7);
            const unsigned short* gp = &v[((size_t)(b * NC + c)) * NL + m0 + g * 8];
            __builtin_amdgcn_global_load_lds(
                (const __attribute__((address_space(1))) unsigned int*)gp,
                (__attribute__((address_space(3))) unsigned int*)&Vd[il * 512],
                16, 0, 0);
        }
    };

    const int q    = qg * 16 + ln15;           // this lane's q row
    const int pwof = q * 128 + (((kg * 32) + quad * 8) ^ ((q & 7) << 4));
    int prof[2];
    #pragma unroll
    for (int jw = 0; jw < 2; ++jw)
        prof[jw] = q * 128 + ((jw * 64 + quad * 16) ^ ((q & 7) << 4));

    stageK(0, Kb0);
    __syncthreads();   // K(0) ready

    for (int mt = 0; mt <= 32; ++mt) {
        // ---- issue staging for this region (K one tile ahead, V current) ----
        if (mt < 31) stageK(mt + 1, (mt & 1) ? Kb0 : Kb1);
        if (mt < 32) stageV(mt, (mt & 1) ? Vb1 : Vb0);

        // ---- QK(mt): swapped MFMA, A=K rows (16 keys of quarter kg),
        //      B=Q resident. Lane -> P[key=kg*16+quad*4+r][q]. Two
        //      accumulators halve the dependent-chain depth. ----
        f32x4 sacc0 = f32x4{0.f, 0.f, 0.f, 0.f};
        f32x4 sacc1 = f32x4{0.f, 0.f, 0.f, 0.f};
        if (mt < 32) {
            const unsigned short* Kd = (mt & 1) ? Kb1 : Kb0;
            const int n = kg * 16 + ln15;      // key row in Kd
            #pragma unroll
            for (int kt = 0; kt < 8; kt += 2) {
                const int p0 = (kt * 4 + quad) ^ (n & 15);
                const int p1 = ((kt + 1) * 4 + quad) ^ (n & 15);
                bf16x8 kf0 = __builtin_bit_cast(bf16x8,
                               *(const u32x4*)&Kd[n * 256 + p0 * 8]);
                bf16x8 kf1 = __builtin_bit_cast(bf16x8,
                               *(const u32x4*)&Kd[n * 256 + p1 * 8]);
                sacc0 = __builtin_amdgcn_mfma_f32_16x16x32_bf16(
                            kf0, qf[kt], sacc0, 0, 0, 0);
                sacc1 = __builtin_amdgcn_mfma_f32_16x16x32_bf16(
                            kf1, qf[kt + 1], sacc1, 0, 0, 0);
            }
        }

        // ---- PV(mt-1): independent of QK(mt); overlaps it ----
        if (mt > 0) {
            const char* Pr = ((mt - 1) & 1) ? P1 : P0;
            const unsigned short* Vd = ((mt - 1) & 1) ? Vb1 : Vb0;
            bf16x8 pa[2];
            #pragma unroll
            for (int jw = 0; jw < 2; ++jw)
                pa[jw] = __builtin_bit_cast(bf16x8, *(const u32x4*)(Pr + prof[jw]));
            dacc = __builtin_amdgcn_mfma_f32_16x16x32_bf16(pa[0], onesf, dacc, 0, 0, 0);
            dacc = __builtin_amdgcn_mfma_f32_16x16x32_bf16(pa[1], onesf, dacc, 0, 0, 0);
            #pragma unroll
            for (int ct = 0; ct < 4; ++ct) {
                const int c = kg * 64 + ct * 16 + ln15;
                #pragma unroll
                for (int jw = 0; jw < 2; ++jw) {
                    const int p = (jw * 4 + quad) ^ (c & 7);
                    bf16x8 vb = __builtin_bit_cast(bf16x8,
                                  *(const u32x4*)&Vd[c * 64 + p * 8]);
                    ctx[ct] = __builtin_amdgcn_mfma_f32_16x16x32_bf16(
                                  pa[jw], vb, ctx[ct], 0, 0, 0);
                }
            }
        }

        // ---- exp + P store for tile mt (after PV so sacc chain has drained) ----
        if (mt < 32) {
            char* Pw = (mt & 1) ? P1 : P0;
            float e0 = __expf((sacc0[0] + sacc1[0]) * SCALE);
            float e1 = __expf((sacc0[1] + sacc1[1]) * SCALE);
            float e2 = __expf((sacc0[2] + sacc1[2]) * SCALE);
            float e3 = __expf((sacc0[3] + sacc1[3]) * SCALE);
            unsigned int d0 = (unsigned int)f2b(e0) | ((unsigned int)f2b(e1) << 16);
            unsigned int d1 = (unsigned int)f2b(e2) | ((unsigned int)f2b(e3) << 16);
            *(u32x2*)(Pw + pwof) = u32x2{d0, d1};
        }

        __syncthreads();   // region end: P visible, staging landed, bufs safe
    }

    // ---- epilogue: in-register normalize, stage to LDS, residual, store ----
    {
        float rinv[4];
        #pragma unroll
        for (int r = 0; r < 4; ++r) rinv[r] = 1.0f / dacc[r];
        #pragma unroll
        for (int ct = 0; ct < 4; ++ct) {
            const int c = kg * 64 + ct * 16 + ln15;
            #pragma unroll
            for (int r = 0; r < 4; ++r)
                buf[c][qg * 16 + quad * 4 + r] = ctx[ct][r] * rinv[r];
        }
    }
    __syncthreads();

    #pragma unroll
    for (int p = 0; p < 4; ++p) {
        const int f  = t + 1024 * p;      // 0..4095
        const int c  = f >> 4;
        const int lg = (f & 15) * 4;
        const size_t idx = ((size_t)(b * NC + c)) * NL + l0 + lg;
        float4 xv = *(const float4*)&x[idx];
        float4 cv = *(const float4*)&buf[c][lg];
        float4 o = make_float4(cv.x + xv.x, cv.y + xv.y, cv.z + xv.z, cv.w + xv.w);
        *(float4*)&out[idx] = o;
    }
}

// ---------------------------------------------------------------------------
extern "C" void kernel_launch(void* const* d_in, const int* in_sizes, int n_in,
                              void* d_out, int out_size, void* d_ws, size_t ws_size,
                              hipStream_t stream) {
    const float* x  = (const float*)d_in[0];
    const float* Wq = (const float*)d_in[1];
    const float* bq = (const float*)d_in[2];
    const float* Wk = (const float*)d_in[3];
    const float* bk = (const float*)d_in[4];
    const float* Wv = (const float*)d_in[5];
    const float* bv = (const float*)d_in[6];
    float* out = (float*)d_out;

    const size_t plane = (size_t)NB * NC * NL;       // 4.19M elems
    unsigned short* qT  = (unsigned short*)d_ws;
    unsigned short* kT  = qT + plane;
    unsigned short* v   = kT + plane;
    unsigned short* Wbf = v + plane;                 // 3*65536 elems

    wconv_kernel<<<192, 256, 0, stream>>>(Wq, Wk, Wv, Wbf);

    qkv_mfma<<<768, 512, 0, stream>>>(x, Wbf, bq, bk, bv, qT, kT, v);

    attn_kernel<<<256, 1024, 0, stream>>>(qT, kT, v, x, out);
}